// Round 10
// baseline (183.753 us; speedup 1.0000x reference)
//
#include <hip/hip_runtime.h>

typedef __bf16 bf16x8 __attribute__((ext_vector_type(8)));
typedef float f32x4 __attribute__((ext_vector_type(4)));
typedef float f32x16 __attribute__((ext_vector_type(16)));
typedef unsigned short u16;
typedef unsigned int u32;
typedef u16 u16x4 __attribute__((ext_vector_type(4)));
typedef u32 u32x4 __attribute__((ext_vector_type(4)));

__device__ __forceinline__ u16 f2bf(float f) {
    union { float f; u32 u; } x{f};
    u32 r = x.u + 0x7FFFu + ((x.u >> 16) & 1u);  // RNE
    return (u16)(r >> 16);
}

__device__ __forceinline__ float ex2(float x) {
#if __has_builtin(__builtin_amdgcn_exp2f)
    return __builtin_amdgcn_exp2f(x);
#else
    return __expf(x * 0.6931471805599453f);
#endif
}

// packed f32 pair -> bf16x2 in one VALU op (RNE).
__device__ __forceinline__ u32 cvtpk(float a, float b) {
    u32 r;
    asm("v_cvt_pk_bf16_f32 %0, %1, %2" : "=v"(r) : "v"(a), "v"(b));
    return r;
}

// async global->LDS, 16B per lane; LDS dest = wave-uniform base + lane*16
#define GLD16(g, l)                                                            \
    __builtin_amdgcn_global_load_lds(                                          \
        (const __attribute__((address_space(1))) u32*)(g),                     \
        (__attribute__((address_space(3))) u32*)(l), 16, 0, 0)

// ---------------------------------------------------------------------------
// Merged prep: fp32->bf16 convert of x + both weight transposes.
// ---------------------------------------------------------------------------
__global__ __launch_bounds__(256) void prep_all(
    const float* __restrict__ x,
    const float* __restrict__ wq, const float* __restrict__ wp,
    u16* __restrict__ Xb,
    u16* __restrict__ WqT, u16* __restrict__ WpT)
{
    __shared__ u16 tile[32][33];
    int id = blockIdx.x;
    if (id < 6144) {
        int i = id * 256 + threadIdx.x;          // n4 = 8192*768/4 = 1572864 = 6144*256
        float4 f = *(const float4*)(x + (size_t)i * 4);
        u16x4 u = { f2bf(f.x), f2bf(f.y), f2bf(f.z), f2bf(f.w) };
        *(u16x4*)(Xb + (size_t)i * 4) = u;
        return;
    }
    id -= 6144;
    const float* src; u16* dst; int R, C, bx, by;
    if (id < 1728) { src = wq; dst = WqT; R = 768; C = 2304; bx = (id % 72) * 32; by = (id / 72) * 32; }
    else { id -= 1728; src = wp; dst = WpT; R = 768; C = 768; bx = (id % 24) * 32; by = (id / 24) * 32; }
    int xx = threadIdx.x & 31, yy = threadIdx.x >> 5;
    #pragma unroll
    for (int i = 0; i < 32; i += 8)
        tile[yy + i][xx] = f2bf(src[(size_t)(by + yy + i) * C + bx + xx]);
    __syncthreads();
    #pragma unroll
    for (int i = 0; i < 32; i += 8)
        dst[(size_t)(bx + yy + i) * R + by + xx] = tile[xx][yy + i];
}

// ---------------------------------------------------------------------------
// QKV GEMM (unchanged, best-measured): 256x128 tile, 512 thr / 8 waves of
// 64x64, 16x16x32 MFMA, conflict-free XOR-granule pattern, 3-buffer 144 KiB
// LDS, stage-ahead-2, counted vmcnt(6), 2-phase fine interleave.
// Grid 576 = 32 row-tiles x 18 col-tiles, XCD-chunked bijectively (8*72).
// V-section (bn>=1536) swaps MFMA operands -> Vt scatter.
// ---------------------------------------------------------------------------
#define MFMA16 __builtin_amdgcn_mfma_f32_16x16x32_bf16

#define STG_P0(tt)                                                              \
    {                                                                           \
        u16* ab_ = &lds[((tt) % 3) * 24576];                                    \
        GLD16(Ap + (tt) * 64 + (size_t)0 * 8 * K, &ab_[(wave * 32 + 0)  * 64]); \
        GLD16(Ap + (tt) * 64 + (size_t)1 * 8 * K, &ab_[(wave * 32 + 8)  * 64]); \
        GLD16(Ap + (tt) * 64 + (size_t)2 * 8 * K, &ab_[(wave * 32 + 16) * 64]); \
    }
#define STG_P1(tt)                                                              \
    {                                                                           \
        u16* ab_ = &lds[((tt) % 3) * 24576];                                    \
        GLD16(Ap + (tt) * 64 + (size_t)3 * 8 * K, &ab_[(wave * 32 + 24) * 64]); \
        GLD16(Bp + (tt) * 64 + (size_t)0 * 8 * K, &ab_[16384 + (wave * 16 + 0) * 64]); \
        GLD16(Bp + (tt) * 64 + (size_t)1 * 8 * K, &ab_[16384 + (wave * 16 + 8) * 64]); \
    }

template <int K>
__global__ __launch_bounds__(512, 1) void gemm_qkv(
    const u16* __restrict__ A,
    const u16* __restrict__ Wt,
    u16* __restrict__ QKV,
    u16* __restrict__ Vt,
    float qscale)
{
    extern __shared__ __align__(16) u16 lds[];   // 3 * (256*64 + 128*64) u16 = 144 KiB

    constexpr int NT = K / 64;   // 12 K-tiles

    int tid = threadIdx.x;
    int wave = tid >> 6, lane = tid & 63;
    int quad = lane >> 4, l16 = lane & 15;
    int wm = (wave >> 1) * 64;      // 4 M-waves: 0,64,128,192
    int wn = (wave & 1) * 64;       // 2 N-waves: 0,64

    int id = blockIdx.x;
    int lin = (id & 7) * 72 + (id >> 3);    // XCD-chunked, bijective (576 = 8*72)
    int bm = (lin / 18) * 256;              // 32 row-tiles
    int bn = (lin % 18) * 128;              // 18 col-tiles
    bool vsec = (bn >= 1536);

    f32x4 acc[4][4] = {};

    int srow = lane >> 3;
    int scg = ((lane & 7) ^ srow) * 8;
    const u16* Ap = A  + (size_t)(bm + wave * 32 + srow) * K + scg;
    const u16* Bp = Wt + (size_t)(bn + wave * 16 + srow) * K + scg;

    int fg0 = ((0 * 4 + quad) ^ (l16 & 7)) * 8;
    int fg1 = ((1 * 4 + quad) ^ (l16 & 7)) * 8;

    // prologue: stage tiles 0,1 (12 loads/thread); wait tile 0 (6 in flight)
    STG_P0(0); STG_P1(0);
    STG_P0(1); STG_P1(1);
    asm volatile("s_waitcnt vmcnt(6)" ::: "memory");
    __builtin_amdgcn_s_barrier();

    #pragma unroll 3
    for (int t = 0; t < NT; ++t) {
        const u16* Ab = &lds[(t % 3) * 24576];
        const u16* Bb = Ab + 16384;

        // ---- phase 0 (k-half 0): 8 ds_reads + 3 staging -> bar -> 16 MFMA -> bar
        {
            bf16x8 af[4], bfr[4];
            #pragma unroll
            for (int i = 0; i < 4; i++) {
                af[i]  = *(const bf16x8*)&Ab[(wm + i * 16 + l16) * 64 + fg0];
                bfr[i] = *(const bf16x8*)&Bb[(wn + i * 16 + l16) * 64 + fg0];
            }
            if (t + 2 < NT) STG_P0(t + 2);
            __builtin_amdgcn_s_barrier();
            __builtin_amdgcn_s_setprio(1);
            if (!vsec) {
                #pragma unroll
                for (int mi = 0; mi < 4; mi++)
                    #pragma unroll
                    for (int ni = 0; ni < 4; ni++)
                        acc[mi][ni] = MFMA16(af[mi], bfr[ni], acc[mi][ni], 0, 0, 0);
            } else {
                #pragma unroll
                for (int mi = 0; mi < 4; mi++)
                    #pragma unroll
                    for (int ni = 0; ni < 4; ni++)
                        acc[mi][ni] = MFMA16(bfr[ni], af[mi], acc[mi][ni], 0, 0, 0);
            }
            __builtin_amdgcn_s_setprio(0);
            __builtin_amdgcn_s_barrier();
        }

        // ---- phase 1 (k-half 1): 8 ds_reads + 3 staging -> bar -> 16 MFMA -> boundary
        {
            bf16x8 af[4], bfr[4];
            #pragma unroll
            for (int i = 0; i < 4; i++) {
                af[i]  = *(const bf16x8*)&Ab[(wm + i * 16 + l16) * 64 + fg1];
                bfr[i] = *(const bf16x8*)&Bb[(wn + i * 16 + l16) * 64 + fg1];
            }
            if (t + 2 < NT) STG_P1(t + 2);
            __builtin_amdgcn_s_barrier();
            __builtin_amdgcn_s_setprio(1);
            if (!vsec) {
                #pragma unroll
                for (int mi = 0; mi < 4; mi++)
                    #pragma unroll
                    for (int ni = 0; ni < 4; ni++)
                        acc[mi][ni] = MFMA16(af[mi], bfr[ni], acc[mi][ni], 0, 0, 0);
            } else {
                #pragma unroll
                for (int mi = 0; mi < 4; mi++)
                    #pragma unroll
                    for (int ni = 0; ni < 4; ni++)
                        acc[mi][ni] = MFMA16(bfr[ni], af[mi], acc[mi][ni], 0, 0, 0);
            }
            __builtin_amdgcn_s_setprio(0);
            // boundary: t+1's 6 loads must be done; t+2's 6 stay in flight
            if (t + 1 < NT) {
                if (t + 2 < NT) { asm volatile("s_waitcnt vmcnt(6)" ::: "memory"); }
                else            { asm volatile("s_waitcnt vmcnt(0)" ::: "memory"); }
            }
            __builtin_amdgcn_s_barrier();
        }
    }

    if (!vsec) {
        float sc = (bn < 768) ? qscale : 1.0f;   // col-tile is uniformly Q or K
        #pragma unroll
        for (int mi = 0; mi < 4; mi++) {
            #pragma unroll
            for (int ni = 0; ni < 4; ni++) {
                #pragma unroll
                for (int rg = 0; rg < 4; rg++) {
                    int row = bm + wm + mi * 16 + quad * 4 + rg;
                    int col = bn + wn + ni * 16 + l16;
                    QKV[(size_t)row * 2304 + col] = f2bf(acc[mi][ni][rg] * sc);
                }
            }
        }
    } else {
        #pragma unroll
        for (int mi = 0; mi < 4; mi++) {
            #pragma unroll
            for (int ni = 0; ni < 4; ni++) {
                #pragma unroll
                for (int rg = 0; rg < 4; rg++) {
                    int d = (bn - 1536) + wn + ni * 16 + quad * 4 + rg;
                    int ng = bm + wm + mi * 16 + l16;
                    int b = ng >> 10, n = ng & 1023, h = d >> 6;
                    Vt[((size_t)(b * 12 + h) * 64 + (d & 63)) * 1024 + n] = f2bf(acc[mi][ni][rg]);
                }
            }
        }
    }
}

#undef STG_P0
#undef STG_P1

// ---------------------------------------------------------------------------
// Output projection GEMM, R10: R0-proven body + XCD row-affinity swizzle.
// Flat grid 384 = 8 XCDs x 48; each XCD owns 8 complete row-panels, so its
// working set (8 x 192 KB A-panels + 1.2 MB B) fits the 4 MB per-XCD L2,
// and each A-panel is fetched once per XCD instead of 6x.
// ---------------------------------------------------------------------------
template <int K>
__global__ __launch_bounds__(256) void gemm_proj(
    const u16* __restrict__ A,
    const u16* __restrict__ Bt,
    float* __restrict__ Cp,
    const float* __restrict__ bias,
    int M, int N)
{
    __shared__ __align__(16) u16 As[128 * 64];
    __shared__ __align__(16) u16 Bs[128 * 64];

    int tid = threadIdx.x;
    int wave = tid >> 6, lane = tid & 63;
    int quad = lane >> 4, l16 = lane & 15;
    int wm = (wave >> 1) * 64, wn = (wave & 1) * 64;

    int id = blockIdx.x;
    int lin = (id & 7) * 48 + (id >> 3);   // XCD-chunked, bijective (384 = 8*48)
    int bm = (lin / 6) * 128;              // 64 row-tiles
    int bn = (lin % 6) * 128;              // 6 col-tiles

    f32x4 acc[4][4] = {};

    int srow = lane >> 3;
    int scg = ((lane & 7) ^ srow) * 8;
    const u16* Ap = A + (size_t)(bm + wave * 32 + srow) * K + scg;
    const u16* Bp = Bt + (size_t)(bn + wave * 32 + srow) * K + scg;

    int fg0 = (((0 * 4 + quad) ^ (l16 & 7)) * 8);
    int fg1 = (((1 * 4 + quad) ^ (l16 & 7)) * 8);

    for (int k0 = 0; k0 < K; k0 += 64) {
        #pragma unroll
        for (int j = 0; j < 4; j++) {
            GLD16(Ap + k0 + (size_t)j * 8 * K, &As[(wave * 32 + j * 8) * 64]);
            GLD16(Bp + k0 + (size_t)j * 8 * K, &Bs[(wave * 32 + j * 8) * 64]);
        }
        __syncthreads();

        #pragma unroll
        for (int h = 0; h < 2; h++) {
            int fg = h ? fg1 : fg0;
            bf16x8 af[4], bfr[4];
            #pragma unroll
            for (int i = 0; i < 4; i++) {
                af[i]  = *(const bf16x8*)&As[(wm + i * 16 + l16) * 64 + fg];
                bfr[i] = *(const bf16x8*)&Bs[(wn + i * 16 + l16) * 64 + fg];
            }
            #pragma unroll
            for (int mi = 0; mi < 4; mi++)
                #pragma unroll
                for (int ni = 0; ni < 4; ni++)
                    acc[mi][ni] = __builtin_amdgcn_mfma_f32_16x16x32_bf16(af[mi], bfr[ni], acc[mi][ni], 0, 0, 0);
        }
        __syncthreads();
    }

    #pragma unroll
    for (int mi = 0; mi < 4; mi++) {
        #pragma unroll
        for (int ni = 0; ni < 4; ni++) {
            #pragma unroll
            for (int rg = 0; rg < 4; rg++) {
                int row = bm + wm + mi * 16 + quad * 4 + rg;
                int col = bn + wn + ni * 16 + l16;
                Cp[(size_t)row * N + col] = acc[mi][ni][rg] + bias[col];
            }
        }
    }
}

// ---------------------------------------------------------------------------
// Flash attention v4, R10: lsum ones-MFMA replaced by in-loop f32 VALU
// accumulation (-4 of 20 MFMAs/tile/wave; the adds dual-issue against MFMA
// and free 15 VGPR). Lanes l and l^32 hold complementary key-quads, so one
// shfl_xor(32) at the end completes the row-sum; the epilogue broadcasts
// lsum[row] via per-lane-index __shfl. XCD-affinity swizzle from R9 kept.
// ---------------------------------------------------------------------------
__global__ __launch_bounds__(256, 3) void attn_kernel(
    const u16* __restrict__ qkv,
    const u16* __restrict__ Vt,
    u16* __restrict__ ctx)
{
    __shared__ __align__(16) u16 Ks[2][4096];   // 2 x 64key x 64d (swizzled)
    __shared__ __align__(16) u16 Vs[2][4096];   // 2 x 64d x 64key (swizzled)

    int id = blockIdx.x;            // 0..767
    int xcd = id & 7;
    int pos = id >> 3;              // 0..95
    int bh = xcd * 12 + (pos >> 3); // 12 bh per XCD
    int qt = pos & 7;               // 8 q-tiles per bh
    int b = bh / 12, h = bh % 12;
    int tid = threadIdx.x;
    int wave = tid >> 6, lane = tid & 63;
    int l32 = lane & 31, half = lane >> 5;

    const u16* qbase = qkv + (size_t)(b * 1024 + qt * 128 + wave * 32 + l32) * 2304 + h * 64;
    bf16x8 qa[4];
    #pragma unroll
    for (int ks = 0; ks < 4; ks++)
        qa[ks] = *(const bf16x8*)(qbase + ks * 16 + half * 8);

    int srow = lane >> 3;
    int scol = (lane & 7) ^ srow;
    const u16* kA = qkv + (size_t)(b * 1024 + wave * 16 + srow) * 2304 + 768 + h * 64 + scol * 8;
    const u16* vA = Vt + ((size_t)bh * 64 + wave * 16 + srow) * 1024 + scol * 8;

    f32x16 o0 = {}, o1 = {};
    float tsum = 0.0f;              // this lane's partial softmax denominator (q = l32)

    int fgo[4];
    #pragma unroll
    for (int ks = 0; ks < 4; ks++)
        fgo[ks] = (((ks * 2 + half) ^ (lane & 7)) * 8);

    {
        GLD16(kA,            &Ks[0][(wave * 2 + 0) * 512]);
        GLD16(kA + 8 * 2304, &Ks[0][(wave * 2 + 1) * 512]);
        GLD16(vA,            &Vs[0][(wave * 2 + 0) * 512]);
        GLD16(vA + 8 * 1024, &Vs[0][(wave * 2 + 1) * 512]);
    }

    #pragma unroll 2
    for (int kt = 0; kt < 16; kt++) {
        int buf = kt & 1;
        __syncthreads();   // drains vmcnt(0): buf is populated

        if (kt < 15) {
            const u16* k0 = kA + (size_t)(kt + 1) * (64 * 2304);
            const u16* v0 = vA + (size_t)(kt + 1) * 64;
            GLD16(k0,            &Ks[buf ^ 1][(wave * 2 + 0) * 512]);
            GLD16(k0 + 8 * 2304, &Ks[buf ^ 1][(wave * 2 + 1) * 512]);
            GLD16(v0,            &Vs[buf ^ 1][(wave * 2 + 0) * 512]);
            GLD16(v0 + 8 * 1024, &Vs[buf ^ 1][(wave * 2 + 1) * 512]);
        }

        f32x16 st0 = {}, st1 = {};
        __builtin_amdgcn_s_setprio(1);
        #pragma unroll
        for (int ks = 0; ks < 4; ks++) {
            bf16x8 kf0 = *(const bf16x8*)&Ks[buf][(l32)      * 64 + fgo[ks]];
            bf16x8 kf1 = *(const bf16x8*)&Ks[buf][(32 + l32) * 64 + fgo[ks]];
            st0 = __builtin_amdgcn_mfma_f32_32x32x16_bf16(kf0, qa[ks], st0, 0, 0, 0);
            st1 = __builtin_amdgcn_mfma_f32_32x32x16_bf16(kf1, qa[ks], st1, 0, 0, 0);
        }
        __builtin_amdgcn_s_setprio(0);

        bf16x8 pf[4];
        #pragma unroll
        for (int t = 0; t < 2; t++) {
            u32 pk[8];
            #pragma unroll
            for (int g = 0; g < 4; g++) {
                float p0 = ex2(t ? st1[4 * g + 0] : st0[4 * g + 0]);
                float p1 = ex2(t ? st1[4 * g + 1] : st0[4 * g + 1]);
                float p2 = ex2(t ? st1[4 * g + 2] : st0[4 * g + 2]);
                float p3 = ex2(t ? st1[4 * g + 3] : st0[4 * g + 3]);
                tsum += (p0 + p1) + (p2 + p3);
                pk[2 * g + 0] = cvtpk(p0, p1);
                pk[2 * g + 1] = cvtpk(p2, p3);
            }
            u32 rA0 = __shfl_xor(half ? pk[0] : pk[2], 32);
            u32 rA1 = __shfl_xor(half ? pk[1] : pk[3], 32);
            u32 rB0 = __shfl_xor(half ? pk[4] : pk[6], 32);
            u32 rB1 = __shfl_xor(half ? pk[5] : pk[7], 32);
            u32x4 f0 = { half ? rA0 : pk[0], half ? rA1 : pk[1],
                         half ? pk[2] : rA0, half ? pk[3] : rA1 };
            u32x4 f1 = { half ? rB0 : pk[4], half ? rB1 : pk[5],
                         half ? pk[6] : rB0, half ? pk[7] : rB1 };
            union { u32x4 u; bf16x8 b; } c0{f0}, c1{f1};
            pf[2 * t + 0] = c0.b;
            pf[2 * t + 1] = c1.b;
        }

        __builtin_amdgcn_s_setprio(1);
        #pragma unroll
        for (int ks = 0; ks < 4; ks++) {
            bf16x8 v0f = *(const bf16x8*)&Vs[buf][(l32)      * 64 + fgo[ks]];
            bf16x8 v1f = *(const bf16x8*)&Vs[buf][(32 + l32) * 64 + fgo[ks]];
            o0 = __builtin_amdgcn_mfma_f32_32x32x16_bf16(pf[ks], v0f, o0, 0, 0, 0);
            o1 = __builtin_amdgcn_mfma_f32_32x32x16_bf16(pf[ks], v1f, o1, 0, 0, 0);
        }
        __builtin_amdgcn_s_setprio(0);
    }

    // combine key-halves: lanes l and l^32 hold complementary key sets for q=l&31
    float fullsum = tsum + __shfl_xor(tsum, 32);

    #pragma unroll
    for (int reg = 0; reg < 16; reg++) {
        int row = (reg & 3) + 8 * (reg >> 2) + 4 * half;
        float inv = 1.0f / __shfl(fullsum, row);   // lane `row` holds q=row
        int qrow = qt * 128 + wave * 32 + row;
        size_t base = (size_t)(b * 1024 + qrow) * 768 + h * 64 + l32;
        ctx[base]      = f2bf(o0[reg] * inv);
        ctx[base + 32] = f2bf(o1[reg] * inv);
    }
}

// ---------------------------------------------------------------------------
extern "C" void kernel_launch(void* const* d_in, const int* in_sizes, int n_in,
                              void* d_out, int out_size, void* d_ws, size_t ws_size,
                              hipStream_t stream) {
    const float* x      = (const float*)d_in[0];  // [8,1024,768]
    const float* w_qkv  = (const float*)d_in[1];  // [768,2304]
    const float* w_proj = (const float*)d_in[2];  // [768,768]
    const float* b_proj = (const float*)d_in[3];  // [768]
    float* out = (float*)d_out;

    const int BN = 8192;     // B*N
    const int C = 768, C3 = 2304;
    const float CE = 0.18033688011112042f;  // 0.125 * log2(e)

    u16* Xb      = (u16*)d_ws;                       // 8192*768
    u16* Wqkv_t  = Xb + (size_t)BN * C;              // 2304*768
    u16* Wproj_t = Wqkv_t + (size_t)C3 * C;          // 768*768
    u16* QKV     = Wproj_t + (size_t)C * C;          // 8192*2304 (Q,K used)
    u16* Vt      = QKV + (size_t)BN * C3;            // 96*64*1024
    u16* Ctx     = Vt + (size_t)96 * 64 * 1024;      // 8192*768

    static bool s_attr = false;
    if (!s_attr) {
        (void)hipFuncSetAttribute((const void*)gemm_qkv<768>,
                                  hipFuncAttributeMaxDynamicSharedMemorySize, 147456);
        s_attr = true;
    }

    prep_all<<<8448, 256, 0, stream>>>(x, w_qkv, w_proj, Xb, Wqkv_t, Wproj_t);

    gemm_qkv<768><<<576, 512, 147456, stream>>>(Xb, Wqkv_t, QKV, Vt, CE);

    attn_kernel<<<768, 256, 0, stream>>>(QKV, Vt, Ctx);

    gemm_proj<768><<<384, 256, 0, stream>>>(
        Ctx, Wproj_t, out, b_proj, BN, C);
}